// Round 9
// baseline (103.348 us; speedup 1.0000x reference)
//
#include <hip/hip_runtime.h>
#include <math.h>

#define NCLS 80
#define BINS 17
#define REGMAX 16
#define NG 32
#define NB 16
#define KTOP 10
#define RAD 2.5f

// ---------- workspace layout (bytes) ----------
#define WS_ACC   0
#define WS_NPOS  32
#define WS_DFLN  224
#define WS_ANYP  416
#define WS_CNT   608
#define WS_FB    640
#define NBLOCKS  (132 * 16)

// focal_bce with t=0: ce*0.75*p^2   (single exp + single log)
__device__ __forceinline__ float focal0(float x) {
    float e   = __expf(-fabsf(x));
    float inv = 1.0f / (1.0f + e);
    float p   = (x >= 0.0f) ? inv : e * inv;          // sigmoid(x)
    float ce  = fmaxf(x, 0.0f) + __logf(1.0f + e);
    return ce * 0.75f * p * p;
}

__device__ __forceinline__ float focal_t(float x, float t) {
    float e   = __expf(-fabsf(x));
    float inv = 1.0f / (1.0f + e);
    float p   = (x >= 0.0f) ? inv : e * inv;
    float ce  = fmaxf(x, 0.0f) - x * t + __logf(1.0f + e);
    float pt  = p * t + (1.0f - p) * (1.0f - t);
    float at  = 0.25f * t + 0.75f * (1.0f - t);
    float om  = 1.0f - pt;
    return ce * at * om * om;
}

// ---- prep: zero accumulators, exact any_pos via windowed scan, fallback ----
__global__ void k_prep(const float* __restrict__ gtb,
                       float* __restrict__ acc, float* __restrict__ npos,
                       float* __restrict__ dfln, int* __restrict__ anyp,
                       int* __restrict__ cnt, int* __restrict__ fb) {
    int lvl = blockIdx.x;
    int tid = threadIdx.x;               // 512 threads: b = tid>>5, g = tid&31
    int b = tid >> 5, g = tid & 31;
    int W = (lvl == 0) ? 80 : (lvl == 1 ? 40 : 20);
    float inv_s = (lvl == 0) ? 0.125f : (lvl == 1 ? 0.0625f : 0.03125f);
    if (lvl == 0) {
        if (tid < 2)  acc[tid] = 0.0f;
        if (tid < 48) { npos[tid] = 0.0f; dfln[tid] = 0.0f; }
        if (tid == 48) *cnt = 0;
    }
    __shared__ int s_any[NB];
    if (tid < NB) s_any[tid] = 0;
    __syncthreads();

    const float* bb = gtb + (b * NG + g) * 4;
    float x1 = bb[0] * inv_s, y1 = bb[1] * inv_s;
    float x2 = bb[2] * inv_s, y2 = bb[3] * inv_s;
    float gcx = (x1 + x2) * 0.5f, gcy = (y1 + y2) * 0.5f;
    int j0 = max((int)floorf(gcx) - 4, 0), j1 = min((int)floorf(gcx) + 4, W - 1);
    int i0 = max((int)floorf(gcy) - 4, 0), i1 = min((int)floorf(gcy) + 4, W - 1);
    bool any = false;
    for (int i = i0; i <= i1; ++i) {
        float cy = (float)i + 0.5f;
        for (int j = j0; j <= j1; ++j) {
            float cx = (float)j + 0.5f;
            bool m = (cx - x1 > 0.0f) && (cy - y1 > 0.0f) &&
                     (x2 - cx > 0.0f) && (y2 - cy > 0.0f) &&
                     (cx >= gcx - RAD) && (cx <= gcx + RAD) &&
                     (cy >= gcy - RAD) && (cy <= gcy + RAD);
            any = any || m;
        }
    }
    if (any) atomicOr(&s_any[b], 1);
    __syncthreads();
    if (g == 0) anyp[lvl * NB + b] = s_any[b];

    if (!s_any[b]) {
        float bd[KTOP]; int bi[KTOP];
        for (int t = 0; t < KTOP; ++t) { bd[t] = 3.0e38f; bi[t] = 0; }
        int HW = W * W;
        for (int p = 0; p < HW; ++p) {
            float cx = (float)(p % W) + 0.5f;
            float cy = (float)(p / W) + 0.5f;
            float dx = cx - gcx, dy = cy - gcy;
            float d = dx * dx + dy * dy;
            if (d < bd[KTOP - 1]) {
                int t = KTOP - 1;
                while (t > 0 && d < bd[t - 1]) { bd[t] = bd[t-1]; bi[t] = bi[t-1]; --t; }
                bd[t] = d; bi[t] = p;
            }
        }
        int* o = fb + ((lvl * NB + b) * NG + g) * KTOP;
        for (int t = 0; t < KTOP; ++t) o[t] = bi[t];
    }
}

// ---- main: 64-pt tiles, float4 streaming, 16 interleaved rows, online LSE ----
__global__ __launch_bounds__(256, 8) void k_main_f(
    const float* __restrict__ reg0, const float* __restrict__ cls0,
    const float* __restrict__ reg1, const float* __restrict__ cls1,
    const float* __restrict__ reg2, const float* __restrict__ cls2,
    const float* __restrict__ gtb,  const int* __restrict__ lab,
    const int* __restrict__ anyp,   const int* __restrict__ fb,
    float* __restrict__ acc, float* __restrict__ npos, float* __restrict__ dfln,
    int* __restrict__ cnt, float* __restrict__ out)
{
    int bx = blockIdx.x;
    int b  = blockIdx.y;
    int lvl, tix, W; const float *regp, *clsp; float inv_s;
    if (bx < 100)      { lvl = 0; tix = bx;       W = 80; regp = reg0; clsp = cls0; inv_s = 0.125f;   }
    else if (bx < 125) { lvl = 1; tix = bx - 100; W = 40; regp = reg1; clsp = cls1; inv_s = 0.0625f;  }
    else               { lvl = 2; tix = bx - 125; W = 20; regp = reg2; clsp = cls2; inv_s = 0.03125f; }
    int HW = W * W;
    int tile = tix * 64;

    int r  = threadIdx.x & 15;           // row 0..15 (interleaved across waves)
    int li = threadIdx.x >> 4;           // lane-in-row 0..15
    int p0 = tile + 4 * li;              // this thread's 4 points p0..p0+3
    bool v = p0 < HW;                    // HW%4==0 -> all-4 valid or all invalid
    int pb = min(p0, HW - 4);            // clamped load base

    __shared__ float s_dv[4][64], s_lz[4][64], s_fzp[12][64], s_fzs[64];
    __shared__ float s_bx[NG][6];
    __shared__ int   s_lab[NG];
    __shared__ unsigned char s_ps[16][16];

    // --- stage boxes + labels into LDS ---
    if (threadIdx.x < NG) {
        int g = threadIdx.x;
        float4 bb4 = *(const float4*)(gtb + (b * NG + g) * 4);
        float x1 = bb4.x * inv_s, y1 = bb4.y * inv_s;
        float x2 = bb4.z * inv_s, y2 = bb4.w * inv_s;
        s_bx[g][0] = x1; s_bx[g][1] = y1; s_bx[g][2] = x2; s_bx[g][3] = y2;
        s_bx[g][4] = (x1 + x2) * 0.5f; s_bx[g][5] = (y1 + y2) * 0.5f;
        s_lab[g] = lab[b * NG + g];
    }

    // --- streaming phase: rows 0-3 = DFL dist r (17 bins, online LSE);
    //     rows 4-11 = 7 classes each; rows 12-15 = 6 classes each ---
    bool is_sm = r < 4;
    int q = r - 4;
    int nt, ch0; const float* arr;
    if (is_sm)      { nt = 17; ch0 = b * 68 + r * 17;              arr = regp; }
    else if (q < 8) { nt = 7;  ch0 = b * 80 + q * 7;               arr = clsp; }
    else            { nt = 6;  ch0 = b * 80 + 56 + (q - 8) * 6;    arr = clsp; }
    const float* bp = arr + (size_t)ch0 * HW + pb;

    float m[4], sm[4], ex[4], fz[4];
#pragma unroll
    for (int j = 0; j < 4; ++j) { m[j] = -3.0e38f; sm[j] = 0.f; ex[j] = 0.f; fz[j] = 0.f; }

#pragma unroll
    for (int t = 0; t < 17; ++t) {
        if (t < nt) {
            float4 x4 = *(const float4*)bp;
            float xv[4] = { x4.x, x4.y, x4.z, x4.w };
            if (is_sm) {
#pragma unroll
                for (int j = 0; j < 4; ++j) {
                    float nm = fmaxf(m[j], xv[j]);
                    float a  = __expf(m[j] - nm);
                    float bb = __expf(xv[j] - nm);
                    sm[j] = sm[j] * a + bb;
                    ex[j] = ex[j] * a + bb * (float)t;
                    m[j]  = nm;
                }
            } else {
#pragma unroll
                for (int j = 0; j < 4; ++j) fz[j] += focal0(xv[j]);
            }
        }
        bp += HW;
    }
    if (is_sm) {
#pragma unroll
        for (int j = 0; j < 4; ++j) {
            s_dv[r][4 * li + j] = ex[j] / sm[j];
            s_lz[r][4 * li + j] = __logf(sm[j]) + m[j];
        }
    } else {
#pragma unroll
        for (int j = 0; j < 4; ++j) s_fzp[q][4 * li + j] = fz[j];
    }
    __syncthreads();

    // --- fzs combine (one thread per point) ---
    if (threadIdx.x < 64) {
        int x = threadIdx.x;
        float f = 0.f;
#pragma unroll
        for (int qq = 0; qq < 12; ++qq) f += s_fzp[qq][x];
        s_fzs[x] = f;
    }
    __syncthreads();

    // --- g-phase: this thread: its 4 points x g in {r, r+16} ---
    bool anyb = anyp[lvl * NB + b] != 0;
    float bxa = 0.f, cla = 0.f, dfa = 0.f, np = 0.f;
    unsigned posm = 0;

    int ri = p0 / W;                     // 4 consecutive points share a row
    float cy = (float)ri + 0.5f;
    float cxb = (float)(p0 - ri * W) + 0.5f;

    if (v) {
#pragma unroll
        for (int gi = 0; gi < 2; ++gi) {
            int g = r + 16 * gi;
            float x1 = s_bx[g][0], y1 = s_bx[g][1];
            float x2 = s_bx[g][2], y2 = s_bx[g][3];
            float gx = s_bx[g][4], gy = s_bx[g][5];
            const int* fbp = fb + ((lvl * NB + b) * NG + g) * KTOP;
#pragma unroll
            for (int j = 0; j < 4; ++j) {
                float cx = cxb + (float)j;
                float dl = cx - x1, dt = cy - y1, dr = x2 - cx, db = y2 - cy;
                bool mk;
                if (anyb) {
                    mk = (dl > 0.f) && (dt > 0.f) && (dr > 0.f) && (db > 0.f) &&
                         (cx >= gx - RAD) && (cx <= gx + RAD) &&
                         (cy >= gy - RAD) && (cy <= gy + RAD);
                } else {
                    int pt = p0 + j;
                    mk = false;
                    for (int t = 0; t < KTOP; ++t) mk = mk || (fbp[t] == pt);
                }
                if (mk) {
                    posm |= (1u << j);
                    np += 1.f;
                    int ptl = 4 * li + j, pt = p0 + j;
                    float dv0 = s_dv[0][ptl], dv1 = s_dv[1][ptl];
                    float dv2 = s_dv[2][ptl], dv3 = s_dv[3][ptl];
                    float px1 = cx - dv0, py1 = cy - dv1;
                    float px2 = cx + dv2, py2 = cy + dv3;
                    float pa = (px2 - px1) * (py2 - py1);
                    float ix1 = fmaxf(px1, x1), iy1 = fmaxf(py1, y1);
                    float ix2 = fminf(px2, x2), iy2 = fminf(py2, y2);
                    float iw = fmaxf(ix2 - ix1, 0.f), ih = fmaxf(iy2 - iy1, 0.f);
                    float inter = iw * ih;
                    float ga = (x2 - x1) * (y2 - y1);
                    float iou = inter / (pa + ga - inter + 1e-6f);
                    bxa += 1.f - iou;
                    float ltrb[4] = { dl, dt, dr, db };
#pragma unroll
                    for (int k = 0; k < 4; ++k) {
                        float tt = fminf(fmaxf(ltrb[k], 0.f), 15.9999f);
                        float lf = floorf(tt); int lb = (int)lf;
                        int rb = lb + 1 > REGMAX ? REGMAX : lb + 1;
                        float wl = (float)rb - tt, wr = tt - lf;
                        float lzk = s_lz[k][ptl];
                        float xl = regp[(size_t)(b * 68 + k * BINS + lb) * HW + pt];
                        float xr = regp[(size_t)(b * 68 + k * BINS + rb) * HW + pt];
                        dfa -= (xl - lzk) * wl + (xr - lzk) * wr;
                    }
                    int cc = s_lab[g];
                    float xat = clsp[(size_t)(b * 80 + cc) * HW + pt];
                    cla += s_fzs[ptl] - focal0(xat) + focal_t(xat, iou);
                }
            }
        }
    }
    s_ps[r][li] = (unsigned char)posm;
    __syncthreads();

    // --- cls_neg: one thread per point ---
    if (threadIdx.x < 64) {
        int x = threadIdx.x;
        if (tile + x < HW) {
            unsigned pg = 0;
#pragma unroll
            for (int rr = 0; rr < 16; ++rr) pg |= s_ps[rr][x >> 2];
            if (!((pg >> (x & 3)) & 1u)) cla += s_fzs[x];
        }
    }

    // --- block reduction: 4 values over 256 threads ---
    float v0 = bxa, v1 = cla, v2 = dfa, v3 = np;
    for (int off = 32; off > 0; off >>= 1) {
        v0 += __shfl_down(v0, off);
        v1 += __shfl_down(v1, off);
        v2 += __shfl_down(v2, off);
        v3 += __shfl_down(v3, off);
    }
    __shared__ float red[4][4];
    int wv = threadIdx.x >> 6, lane = threadIdx.x & 63;
    if (lane == 0) { red[wv][0] = v0; red[wv][1] = v1; red[wv][2] = v2; red[wv][3] = v3; }
    __syncthreads();
    if (threadIdx.x == 0) {
        float t0 = 0, t1 = 0, t2 = 0, t3 = 0;
        for (int w = 0; w < 4; ++w) {
            t0 += red[w][0]; t1 += red[w][1]; t2 += red[w][2]; t3 += red[w][3];
        }
        atomicAdd(&acc[0], t0);
        atomicAdd(&acc[1], t1);
        atomicAdd(&dfln[lvl * NB + b], t2);
        atomicAdd(&npos[lvl * NB + b], t3);
    }

    // --- last block finalizes the output ---
    __shared__ int s_tick;
    if (threadIdx.x == 0) {
        __threadfence();
        s_tick = atomicAdd(cnt, 1);
    }
    __syncthreads();
    if (s_tick == NBLOCKS - 1 && threadIdx.x < 64) {
        float vs = 0.f;
        if (lane < 48) {
            float n = atomicAdd(&npos[lane], 0.0f);   // coherent read
            float d = atomicAdd(&dfln[lane], 0.0f);
            if (n > 0.f) vs = d / (n * 4.0f);
        }
        for (int off = 32; off > 0; off >>= 1) vs += __shfl_down(vs, off);
        if (lane == 0) {
            float tbv = atomicAdd(&acc[0], 0.0f);
            float tcv = atomicAdd(&acc[1], 0.0f);
            out[0] = 7.5f * tbv + tcv + 1.5f * vs;
            out[1] = tbv; out[2] = tcv; out[3] = vs;
        }
    }
}

extern "C" void kernel_launch(void* const* d_in, const int* in_sizes, int n_in,
                              void* d_out, int out_size, void* d_ws, size_t ws_size,
                              hipStream_t stream) {
    const float* reg0 = (const float*)d_in[0];
    const float* cls0 = (const float*)d_in[1];
    const float* reg1 = (const float*)d_in[2];
    const float* cls1 = (const float*)d_in[3];
    const float* reg2 = (const float*)d_in[4];
    const float* cls2 = (const float*)d_in[5];
    const float* gtb  = (const float*)d_in[6];
    const int*   lab  = (const int*)d_in[7];
    float* out = (float*)d_out;

    char*  ws   = (char*)d_ws;
    float* acc  = (float*)(ws + WS_ACC);
    float* npos = (float*)(ws + WS_NPOS);
    float* dfln = (float*)(ws + WS_DFLN);
    int*   anyp = (int*)(ws + WS_ANYP);
    int*   cnt  = (int*)(ws + WS_CNT);
    int*   fb   = (int*)(ws + WS_FB);

    k_prep<<<3, 512, 0, stream>>>(gtb, acc, npos, dfln, anyp, cnt, fb);
    // 64-pt tiles: L0 100, L1 25, L2 7 -> 132 x 16 = 2112 blocks, 256 thr
    k_main_f<<<dim3(132, NB), 256, 0, stream>>>(reg0, cls0, reg1, cls1, reg2, cls2,
                                                gtb, lab, anyp, fb,
                                                acc, npos, dfln, cnt, out);
}

// Round 10
// 58.016 us; speedup vs baseline: 1.7814x; 1.7814x over previous
//
#include <hip/hip_runtime.h>
#include <math.h>

#define NCLS 80
#define BINS 17
#define REGMAX 16
#define NG 32
#define NB 16
#define KTOP 10
#define RAD 2.5f

// ---------- workspace layout (bytes) ----------
#define WS_ACC   0
#define WS_NPOS  32
#define WS_DFLN  224
#define WS_ANYP  416
#define WS_CNT   608
#define WS_FB    640
#define NBLOCKS  (34 * 16)

// focal_bce with t=0: ce*0.75*p^2   (single exp + single log)
__device__ __forceinline__ float focal0(float x) {
    float e   = __expf(-fabsf(x));
    float inv = 1.0f / (1.0f + e);
    float p   = (x >= 0.0f) ? inv : e * inv;          // sigmoid(x)
    float ce  = fmaxf(x, 0.0f) + __logf(1.0f + e);
    return ce * 0.75f * p * p;
}

__device__ __forceinline__ float focal_t(float x, float t) {
    float e   = __expf(-fabsf(x));
    float inv = 1.0f / (1.0f + e);
    float p   = (x >= 0.0f) ? inv : e * inv;
    float ce  = fmaxf(x, 0.0f) - x * t + __logf(1.0f + e);
    float pt  = p * t + (1.0f - p) * (1.0f - t);
    float at  = 0.25f * t + 0.75f * (1.0f - t);
    float om  = 1.0f - pt;
    return ce * at * om * om;
}

// ---- prep: zero accumulators, exact any_pos via windowed scan, fallback ----
__global__ void k_prep(const float* __restrict__ gtb,
                       float* __restrict__ acc, float* __restrict__ npos,
                       float* __restrict__ dfln, int* __restrict__ anyp,
                       int* __restrict__ cnt, int* __restrict__ fb) {
    int lvl = blockIdx.x;
    int tid = threadIdx.x;               // 512 threads: b = tid>>5, g = tid&31
    int b = tid >> 5, g = tid & 31;
    int W = (lvl == 0) ? 80 : (lvl == 1 ? 40 : 20);
    float inv_s = (lvl == 0) ? 0.125f : (lvl == 1 ? 0.0625f : 0.03125f);
    if (lvl == 0) {
        if (tid < 2)  acc[tid] = 0.0f;
        if (tid < 48) { npos[tid] = 0.0f; dfln[tid] = 0.0f; }
        if (tid == 48) *cnt = 0;
    }
    __shared__ int s_any[NB];
    if (tid < NB) s_any[tid] = 0;
    __syncthreads();

    const float* bb = gtb + (b * NG + g) * 4;
    float x1 = bb[0] * inv_s, y1 = bb[1] * inv_s;
    float x2 = bb[2] * inv_s, y2 = bb[3] * inv_s;
    float gcx = (x1 + x2) * 0.5f, gcy = (y1 + y2) * 0.5f;
    int j0 = max((int)floorf(gcx) - 4, 0), j1 = min((int)floorf(gcx) + 4, W - 1);
    int i0 = max((int)floorf(gcy) - 4, 0), i1 = min((int)floorf(gcy) + 4, W - 1);
    bool any = false;
    for (int i = i0; i <= i1; ++i) {
        float cy = (float)i + 0.5f;
        for (int j = j0; j <= j1; ++j) {
            float cx = (float)j + 0.5f;
            bool m = (cx - x1 > 0.0f) && (cy - y1 > 0.0f) &&
                     (x2 - cx > 0.0f) && (y2 - cy > 0.0f) &&
                     (cx >= gcx - RAD) && (cx <= gcx + RAD) &&
                     (cy >= gcy - RAD) && (cy <= gcy + RAD);
            any = any || m;
        }
    }
    if (any) atomicOr(&s_any[b], 1);
    __syncthreads();
    if (g == 0) anyp[lvl * NB + b] = s_any[b];

    if (!s_any[b]) {
        float bd[KTOP]; int bi[KTOP];
        for (int t = 0; t < KTOP; ++t) { bd[t] = 3.0e38f; bi[t] = 0; }
        int HW = W * W;
        for (int p = 0; p < HW; ++p) {
            float cx = (float)(p % W) + 0.5f;
            float cy = (float)(p / W) + 0.5f;
            float dx = cx - gcx, dy = cy - gcy;
            float d = dx * dx + dy * dy;
            if (d < bd[KTOP - 1]) {
                int t = KTOP - 1;
                while (t > 0 && d < bd[t - 1]) { bd[t] = bd[t-1]; bi[t] = bi[t-1]; --t; }
                bd[t] = d; bi[t] = p;
            }
        }
        int* o = fb + ((lvl * NB + b) * NG + g) * KTOP;
        for (int t = 0; t < KTOP; ++t) o[t] = bi[t];
    }
}

// ---- main: 256-pt tiles, 8 slice-waves, float4 (1 KB/instr), online LSE ----
__global__ __launch_bounds__(512, 4) void k_main_f(
    const float* __restrict__ reg0, const float* __restrict__ cls0,
    const float* __restrict__ reg1, const float* __restrict__ cls1,
    const float* __restrict__ reg2, const float* __restrict__ cls2,
    const float* __restrict__ gtb,  const int* __restrict__ lab,
    const int* __restrict__ anyp,   const int* __restrict__ fb,
    float* __restrict__ acc, float* __restrict__ npos, float* __restrict__ dfln,
    int* __restrict__ cnt, float* __restrict__ out)
{
    int bx = blockIdx.x;
    int b  = blockIdx.y;
    int lvl, tix, W; const float *regp, *clsp; float inv_s;
    if (bx < 25)      { lvl = 0; tix = bx;      W = 80; regp = reg0; clsp = cls0; inv_s = 0.125f;   }
    else if (bx < 32) { lvl = 1; tix = bx - 25; W = 40; regp = reg1; clsp = cls1; inv_s = 0.0625f;  }
    else              { lvl = 2; tix = bx - 32; W = 20; regp = reg2; clsp = cls2; inv_s = 0.03125f; }
    int HW = W * W;
    int tile = tix * 256;

    int lane = threadIdx.x & 63;
    int s    = threadIdx.x >> 6;         // slice-wave 0..7
    int p0   = tile + 4 * lane;          // this thread's 4 consecutive points
    bool v   = p0 < HW;                  // 4 | HW -> all-or-none valid
    int pb   = v ? p0 : HW - 4;          // clamped, in-bounds load base

    __shared__ float s_dv[4][256], s_lz[4][256], s_fzp[4][256], s_fzs[256];
    __shared__ float s_bx[NG][6];
    __shared__ int   s_lab[NG];
    __shared__ unsigned char s_ps[8][64];

    // --- stage boxes + labels into LDS ---
    if (threadIdx.x < NG) {
        int g = threadIdx.x;
        float4 bb4 = *(const float4*)(gtb + (b * NG + g) * 4);
        float x1 = bb4.x * inv_s, y1 = bb4.y * inv_s;
        float x2 = bb4.z * inv_s, y2 = bb4.w * inv_s;
        s_bx[g][0] = x1; s_bx[g][1] = y1; s_bx[g][2] = x2; s_bx[g][3] = y2;
        s_bx[g][4] = (x1 + x2) * 0.5f; s_bx[g][5] = (y1 + y2) * 0.5f;
        s_lab[g] = lab[b * NG + g];
    }

    // --- streaming phase: 1 KB/instruction wave-contiguous float4 loads ---
    if (s < 4) {
        // waves 0-3: DFL distribution k = s (17 bins), online logsumexp
        const float* bp = regp + (size_t)(b * 68 + s * BINS) * HW + pb;
        float m[4], sm[4], ex[4];
#pragma unroll
        for (int j = 0; j < 4; ++j) { m[j] = -3.0e38f; sm[j] = 0.f; ex[j] = 0.f; }
#pragma unroll
        for (int t = 0; t < BINS; ++t) {
            float4 x4 = *(const float4*)(bp + (size_t)t * HW);
            float xv[4] = { x4.x, x4.y, x4.z, x4.w };
#pragma unroll
            for (int j = 0; j < 4; ++j) {
                float nm = fmaxf(m[j], xv[j]);
                float a  = __expf(m[j] - nm);
                float bb = __expf(xv[j] - nm);
                sm[j] = sm[j] * a + bb;
                ex[j] = ex[j] * a + bb * (float)t;
                m[j]  = nm;
            }
        }
        *(float4*)&s_dv[s][4 * lane] =
            make_float4(ex[0] / sm[0], ex[1] / sm[1], ex[2] / sm[2], ex[3] / sm[3]);
        *(float4*)&s_lz[s][4 * lane] =
            make_float4(__logf(sm[0]) + m[0], __logf(sm[1]) + m[1],
                        __logf(sm[2]) + m[2], __logf(sm[3]) + m[3]);
    } else {
        // waves 4-7: 20 focal0 classes each
        const float* bp = clsp + (size_t)(b * 80 + (s - 4) * 20) * HW + pb;
        float fz[4] = { 0.f, 0.f, 0.f, 0.f };
#pragma unroll
        for (int t = 0; t < 20; ++t) {
            float4 c4 = *(const float4*)(bp + (size_t)t * HW);
            fz[0] += focal0(c4.x); fz[1] += focal0(c4.y);
            fz[2] += focal0(c4.z); fz[3] += focal0(c4.w);
        }
        *(float4*)&s_fzp[s - 4][4 * lane] = make_float4(fz[0], fz[1], fz[2], fz[3]);
    }
    __syncthreads();

    // --- fzs combine (one thread per point) ---
    if (threadIdx.x < 256) {
        int x = threadIdx.x;
        s_fzs[x] = s_fzp[0][x] + s_fzp[1][x] + s_fzp[2][x] + s_fzp[3][x];
    }
    __syncthreads();

    // --- g-phase ---
    bool anyb = anyp[lvl * NB + b] != 0;
    float bxa = 0.f, cla = 0.f, dfa = 0.f, np = 0.f;
    unsigned posm = 0;

    int ri = p0 / W;                     // 4 | W -> 4-pt group never crosses a row
    float cy  = (float)ri + 0.5f;
    float cxb = (float)(p0 - ri * W) + 0.5f;

#define PROC_G(G, GEOM) do {                                               \
    float x1 = s_bx[G][0], y1 = s_bx[G][1];                                \
    float x2 = s_bx[G][2], y2 = s_bx[G][3];                                \
    float gx = s_bx[G][4], gy = s_bx[G][5];                                \
    const int* fbp = fb + ((lvl * NB + b) * NG + (G)) * KTOP;              \
    _Pragma("unroll")                                                      \
    for (int j = 0; j < 4; ++j) {                                          \
        float cx = cxb + (float)j;                                         \
        float dl = cx - x1, dt = cy - y1, dr = x2 - cx, db = y2 - cy;      \
        bool mk;                                                           \
        if (GEOM) {                                                        \
            mk = (dl > 0.f) && (dt > 0.f) && (dr > 0.f) && (db > 0.f) &&   \
                 (cx >= gx - RAD) && (cx <= gx + RAD) &&                   \
                 (cy >= gy - RAD) && (cy <= gy + RAD);                     \
        } else {                                                           \
            int pt = p0 + j;                                               \
            mk = false;                                                    \
            for (int t = 0; t < KTOP; ++t) mk = mk || (fbp[t] == pt);      \
        }                                                                  \
        if (mk) {                                                          \
            posm |= (1u << j);                                             \
            np += 1.f;                                                     \
            int ptl = 4 * lane + j, pt = p0 + j;                           \
            float dv0 = s_dv[0][ptl], dv1 = s_dv[1][ptl];                  \
            float dv2 = s_dv[2][ptl], dv3 = s_dv[3][ptl];                  \
            float px1 = cx - dv0, py1 = cy - dv1;                          \
            float px2 = cx + dv2, py2 = cy + dv3;                          \
            float pa = (px2 - px1) * (py2 - py1);                          \
            float ix1 = fmaxf(px1, x1), iy1 = fmaxf(py1, y1);              \
            float ix2 = fminf(px2, x2), iy2 = fminf(py2, y2);              \
            float iw = fmaxf(ix2 - ix1, 0.f), ih = fmaxf(iy2 - iy1, 0.f);  \
            float inter = iw * ih;                                         \
            float ga = (x2 - x1) * (y2 - y1);                              \
            float iou = inter / (pa + ga - inter + 1e-6f);                 \
            bxa += 1.f - iou;                                              \
            float ltrb[4] = { dl, dt, dr, db };                            \
            _Pragma("unroll")                                              \
            for (int k = 0; k < 4; ++k) {                                  \
                float tt = fminf(fmaxf(ltrb[k], 0.f), 15.9999f);           \
                float lf = floorf(tt); int lb = (int)lf;                   \
                int rb = lb + 1 > REGMAX ? REGMAX : lb + 1;                \
                float wl = (float)rb - tt, wr = tt - lf;                   \
                float lzk = s_lz[k][ptl];                                  \
                float xl = regp[(size_t)(b * 68 + k * BINS + lb) * HW + pt];\
                float xr = regp[(size_t)(b * 68 + k * BINS + rb) * HW + pt];\
                dfa -= (xl - lzk) * wl + (xr - lzk) * wr;                  \
            }                                                              \
            int cc = s_lab[G];                                             \
            float xat = clsp[(size_t)(b * 80 + cc) * HW + pt];             \
            cla += s_fzs[ptl] - focal0(xat) + focal_t(xat, iou);           \
        }                                                                  \
    }                                                                      \
} while (0)

    if (v) {
        if (anyb) {
            // g-culling: row-range overlap test (conservative superset)
            int gg = lane & 31;
            float gy1 = s_bx[gg][1], gy2 = s_bx[gg][3], gcy = s_bx[gg][5];
            int r0 = tile / W;
            int r1 = min(tile + 255, HW - 1) / W;
            float cyLo = (float)r0 + 0.5f, cyHi = (float)r1 + 0.5f;
            bool act = (cyHi > gy1) && (gy2 > cyLo) &&
                       (cyHi >= gcy - RAD) && (cyLo <= gcy + RAD);
            unsigned long long bm = __ballot(act);
            unsigned m32 = (unsigned)(bm | (bm >> 32));
            int ord = 0;
            while (m32) {
                int g = __builtin_ctz(m32); m32 &= m32 - 1;
                if ((ord++ & 7) == s) PROC_G(g, true);
            }
        } else {
#pragma unroll
            for (int gi = 0; gi < 4; ++gi) { int g = s * 4 + gi; PROC_G(g, false); }
        }
    }
    s_ps[s][lane] = (unsigned char)posm;
    __syncthreads();

    // --- cls_neg: one thread per point ---
    if (threadIdx.x < 256) {
        int x = threadIdx.x;
        if (tile + x < HW) {
            unsigned pg = 0;
#pragma unroll
            for (int w = 0; w < 8; ++w) pg |= s_ps[w][x >> 2];
            if (!((pg >> (x & 3)) & 1u)) cla += s_fzs[x];
        }
    }

    // --- block reduction: 4 values over 512 threads ---
    float v0 = bxa, v1 = cla, v2 = dfa, v3 = np;
    for (int off = 32; off > 0; off >>= 1) {
        v0 += __shfl_down(v0, off);
        v1 += __shfl_down(v1, off);
        v2 += __shfl_down(v2, off);
        v3 += __shfl_down(v3, off);
    }
    __shared__ float red[8][4];
    if (lane == 0) { red[s][0] = v0; red[s][1] = v1; red[s][2] = v2; red[s][3] = v3; }
    __syncthreads();
    if (threadIdx.x == 0) {
        float t0 = 0, t1 = 0, t2 = 0, t3 = 0;
        for (int w = 0; w < 8; ++w) {
            t0 += red[w][0]; t1 += red[w][1]; t2 += red[w][2]; t3 += red[w][3];
        }
        atomicAdd(&acc[0], t0);
        atomicAdd(&acc[1], t1);
        atomicAdd(&dfln[lvl * NB + b], t2);
        atomicAdd(&npos[lvl * NB + b], t3);
    }

    // --- last block finalizes the output ---
    __shared__ int s_tick;
    if (threadIdx.x == 0) {
        __threadfence();
        s_tick = atomicAdd(cnt, 1);
    }
    __syncthreads();
    if (s_tick == NBLOCKS - 1 && threadIdx.x < 64) {
        float vs = 0.f;
        if (lane < 48) {
            float n = atomicAdd(&npos[lane], 0.0f);   // coherent read
            float d = atomicAdd(&dfln[lane], 0.0f);
            if (n > 0.f) vs = d / (n * 4.0f);
        }
        for (int off = 32; off > 0; off >>= 1) vs += __shfl_down(vs, off);
        if (lane == 0) {
            float tbv = atomicAdd(&acc[0], 0.0f);
            float tcv = atomicAdd(&acc[1], 0.0f);
            out[0] = 7.5f * tbv + tcv + 1.5f * vs;
            out[1] = tbv; out[2] = tcv; out[3] = vs;
        }
    }
}

extern "C" void kernel_launch(void* const* d_in, const int* in_sizes, int n_in,
                              void* d_out, int out_size, void* d_ws, size_t ws_size,
                              hipStream_t stream) {
    const float* reg0 = (const float*)d_in[0];
    const float* cls0 = (const float*)d_in[1];
    const float* reg1 = (const float*)d_in[2];
    const float* cls1 = (const float*)d_in[3];
    const float* reg2 = (const float*)d_in[4];
    const float* cls2 = (const float*)d_in[5];
    const float* gtb  = (const float*)d_in[6];
    const int*   lab  = (const int*)d_in[7];
    float* out = (float*)d_out;

    char*  ws   = (char*)d_ws;
    float* acc  = (float*)(ws + WS_ACC);
    float* npos = (float*)(ws + WS_NPOS);
    float* dfln = (float*)(ws + WS_DFLN);
    int*   anyp = (int*)(ws + WS_ANYP);
    int*   cnt  = (int*)(ws + WS_CNT);
    int*   fb   = (int*)(ws + WS_FB);

    k_prep<<<3, 512, 0, stream>>>(gtb, acc, npos, dfln, anyp, cnt, fb);
    // 256-pt tiles: L0 25, L1 7, L2 2 -> 34 x 16 = 544 blocks, 512 thr
    k_main_f<<<dim3(34, NB), 512, 0, stream>>>(reg0, cls0, reg1, cls1, reg2, cls2,
                                               gtb, lab, anyp, fb,
                                               acc, npos, dfln, cnt, out);
}